// Round 1
// baseline (938.278 us; speedup 1.0000x reference)
//
#include <hip/hip_runtime.h>
#include <math.h>

#define NFEAT 128
#define NHID 64
#define NCLASS 40

// ---------------- degree / norm ----------------

__global__ void k_init_deg(float* __restrict__ deg, int N) {
    int i = blockIdx.x * blockDim.x + threadIdx.x;
    if (i < N) deg[i] = 1.0f;   // self-loop weight
}

__global__ void k_deg_scatter(const int* __restrict__ dst, const float* __restrict__ w,
                              float* __restrict__ deg, int E) {
    int i = blockIdx.x * blockDim.x + threadIdx.x;
    if (i < E) atomicAdd(&deg[dst[i]], w[i]);
}

__global__ void k_dinv(const float* __restrict__ deg, float* __restrict__ dinv, int N) {
    int i = blockIdx.x * blockDim.x + threadIdx.x;
    if (i < N) dinv[i] = rsqrtf(deg[i]);   // deg >= 1 always
}

__global__ void k_norm(const int* __restrict__ src, const int* __restrict__ dst,
                       const float* __restrict__ w, const float* __restrict__ dinv,
                       float* __restrict__ norm, int E) {
    int i = blockIdx.x * blockDim.x + threadIdx.x;
    if (i < E) norm[i] = dinv[src[i]] * w[i] * dinv[dst[i]];
}

// ---------------- GEMM 1: h1 = x @ W1, x:[N,128] W1:[128,64] ----------------
// 16 rows/block, 256 threads: thread (rg=t>>6, c=t&63) computes rows rg*4..rg*4+3, col c.

__global__ __launch_bounds__(256) void k_gemm1(const float* __restrict__ x,
                                               const float* __restrict__ W,
                                               float* __restrict__ h, int N) {
    __shared__ float Ws[NFEAT * NHID];   // 32 KB
    __shared__ float xs[16][NFEAT];      // 8 KB
    int t = threadIdx.x;
    for (int i = t; i < NFEAT * NHID; i += 256) Ws[i] = W[i];
    int row0 = blockIdx.x * 16;
    for (int i = t; i < 16 * NFEAT; i += 256) {
        int r = i >> 7, k = i & 127;
        int row = row0 + r;
        xs[r][k] = (row < N) ? x[(size_t)row * NFEAT + k] : 0.0f;
    }
    __syncthreads();
    int c = t & 63;
    int rg = t >> 6;   // 0..3
    float acc[4] = {0.f, 0.f, 0.f, 0.f};
    #pragma unroll 4
    for (int k = 0; k < NFEAT; k++) {
        float wv = Ws[k * NHID + c];
        #pragma unroll
        for (int j = 0; j < 4; j++) acc[j] += xs[rg * 4 + j][k] * wv;
    }
    #pragma unroll
    for (int j = 0; j < 4; j++) {
        int row = row0 + rg * 4 + j;
        if (row < N) h[(size_t)row * NHID + c] = acc[j];
    }
}

// ---------------- init out1 = b1 + dinv^2 * h1 (self loop) ----------------

__global__ void k_init_out1(const float* __restrict__ h, const float* __restrict__ dinv,
                            const float* __restrict__ b, float* __restrict__ out, int total) {
    int i = blockIdx.x * blockDim.x + threadIdx.x;
    if (i < total) {
        int row = i >> 6;      // /64
        int c = i & 63;
        float di = dinv[row];
        out[i] = b[c] + di * di * h[i];
    }
}

// ---------------- edge scatter layer 1: out1[dst] += norm * h1[src] ----------------

__global__ void k_scatter1(const int* __restrict__ src, const int* __restrict__ dst,
                           const float* __restrict__ norm, const float* __restrict__ h,
                           float* __restrict__ out, int E) {
    int idx = blockIdx.x * blockDim.x + threadIdx.x;
    int e = idx >> 6;   // 64 threads per edge
    int c = idx & 63;
    if (e < E) {
        float nm = norm[e];
        int s = src[e], d = dst[e];
        atomicAdd(&out[(size_t)d * NHID + c], nm * h[(size_t)s * NHID + c]);
    }
}

// ---------------- GEMM 2: h2 = relu(out1) @ W2, [N,64]x[64,40] ----------------
// 32 rows/block, 320 threads (5 waves): thread (rg=t/40, c=t%40) does 4 rows.

__global__ __launch_bounds__(320) void k_gemm2(const float* __restrict__ a,
                                               const float* __restrict__ W,
                                               float* __restrict__ h, int N) {
    __shared__ float Ws[NHID * NCLASS];  // 10 KB
    __shared__ float xs[32][NHID];       // 8 KB
    int t = threadIdx.x;
    for (int i = t; i < NHID * NCLASS; i += 320) Ws[i] = W[i];
    int row0 = blockIdx.x * 32;
    for (int i = t; i < 32 * NHID; i += 320) {
        int r = i >> 6, k = i & 63;
        int row = row0 + r;
        xs[r][k] = (row < N) ? fmaxf(a[(size_t)row * NHID + k], 0.0f) : 0.0f;  // fused ReLU
    }
    __syncthreads();
    int c = t % NCLASS;
    int rg = t / NCLASS;   // 0..7
    float acc[4] = {0.f, 0.f, 0.f, 0.f};
    #pragma unroll 4
    for (int k = 0; k < NHID; k++) {
        float wv = Ws[k * NCLASS + c];
        #pragma unroll
        for (int j = 0; j < 4; j++) acc[j] += xs[rg * 4 + j][k] * wv;
    }
    #pragma unroll
    for (int j = 0; j < 4; j++) {
        int row = row0 + rg * 4 + j;
        if (row < N) h[(size_t)row * NCLASS + c] = acc[j];
    }
}

// ---------------- init out2 = b2 + dinv^2 * h2 (into d_out) ----------------

__global__ void k_init_out2(const float* __restrict__ h, const float* __restrict__ dinv,
                            const float* __restrict__ b, float* __restrict__ out, int total) {
    int i = blockIdx.x * blockDim.x + threadIdx.x;
    if (i < total) {
        unsigned u = (unsigned)i;
        int row = u / NCLASS;
        int c = u - row * NCLASS;
        float di = dinv[row];
        out[i] = b[c] + di * di * h[i];
    }
}

// ---------------- edge scatter layer 2 ----------------

__global__ void k_scatter2(const int* __restrict__ src, const int* __restrict__ dst,
                           const float* __restrict__ norm, const float* __restrict__ h,
                           float* __restrict__ out, int E) {
    int idx = blockIdx.x * blockDim.x + threadIdx.x;
    unsigned u = (unsigned)idx;
    int e = u / NCLASS;
    int c = u - e * NCLASS;
    if (e < E) {
        float nm = norm[e];
        int s = src[e], d = dst[e];
        atomicAdd(&out[(size_t)d * NCLASS + c], nm * h[(size_t)s * NCLASS + c]);
    }
}

// ---------------- log_softmax, one wave per row (40 cols), in place ----------------

__global__ __launch_bounds__(256) void k_logsoftmax(float* __restrict__ out, int N) {
    int lane = threadIdx.x & 63;
    int row = blockIdx.x * (blockDim.x >> 6) + (threadIdx.x >> 6);
    if (row >= N) return;
    float v = (lane < NCLASS) ? out[(size_t)row * NCLASS + lane] : -INFINITY;
    float m = v;
    #pragma unroll
    for (int off = 32; off > 0; off >>= 1) m = fmaxf(m, __shfl_down(m, off));
    m = __shfl(m, 0);
    float ex = (lane < NCLASS) ? expf(v - m) : 0.0f;
    float s = ex;
    #pragma unroll
    for (int off = 32; off > 0; off >>= 1) s += __shfl_down(s, off);
    s = __shfl(s, 0);
    if (lane < NCLASS) out[(size_t)row * NCLASS + lane] = v - m - logf(s);
}

// ---------------- launch ----------------

extern "C" void kernel_launch(void* const* d_in, const int* in_sizes, int n_in,
                              void* d_out, int out_size, void* d_ws, size_t ws_size,
                              hipStream_t stream) {
    const float* x  = (const float*)d_in[0];
    const int*   ei = (const int*)d_in[1];     // [2,E] int32 per harness convention
    const float* w  = (const float*)d_in[2];
    const float* W1 = (const float*)d_in[3];
    const float* b1 = (const float*)d_in[4];
    const float* W2 = (const float*)d_in[5];
    const float* b2 = (const float*)d_in[6];
    float* out = (float*)d_out;

    const int N = in_sizes[0] / NFEAT;
    const int E = in_sizes[1] / 2;
    const int* src = ei;
    const int* dst = ei + E;

    float* ws   = (float*)d_ws;
    float* deg  = ws;                       // N
    float* dinv = deg + N;                  // N
    float* nrm  = dinv + N;                 // E
    float* h1   = nrm + E;                  // N*64
    float* out1 = h1 + (size_t)N * NHID;    // N*64
    float* h2   = out1 + (size_t)N * NHID;  // N*40

    const int B = 256;
    // norm precompute
    k_init_deg<<<(N + B - 1) / B, B, 0, stream>>>(deg, N);
    k_deg_scatter<<<(E + B - 1) / B, B, 0, stream>>>(dst, w, deg, E);
    k_dinv<<<(N + B - 1) / B, B, 0, stream>>>(deg, dinv, N);
    k_norm<<<(E + B - 1) / B, B, 0, stream>>>(src, dst, w, dinv, nrm, E);

    // layer 1
    k_gemm1<<<(N + 15) / 16, 256, 0, stream>>>(x, W1, h1, N);
    k_init_out1<<<((size_t)N * NHID + B - 1) / B, B, 0, stream>>>(h1, dinv, b1, out1, N * NHID);
    k_scatter1<<<((size_t)E * 64 + B - 1) / B, B, 0, stream>>>(src, dst, nrm, h1, out1, E);

    // layer 2 (ReLU fused into GEMM2 load)
    k_gemm2<<<(N + 31) / 32, 320, 0, stream>>>(out1, W2, h2, N);
    k_init_out2<<<((size_t)N * NCLASS + B - 1) / B, B, 0, stream>>>(h2, dinv, b2, out, N * NCLASS);
    k_scatter2<<<((size_t)E * NCLASS + B - 1) / B, B, 0, stream>>>(src, dst, nrm, h2, out, E);

    // log_softmax in place on d_out
    k_logsoftmax<<<(N + 3) / 4, 256, 0, stream>>>(out, N);
}

// Round 2
// 576.863 us; speedup vs baseline: 1.6265x; 1.6265x over previous
//
#include <hip/hip_runtime.h>
#include <math.h>

#define NFEAT 128
#define NHID 64
#define NCLASS 40
#define SCAN_CHUNK 1024   // elems per scan block (256 thr x 4)

// ---------------- CSR build ----------------

__global__ void k_setup(int* __restrict__ cnt, float* __restrict__ deg, int N) {
    int i = blockIdx.x * blockDim.x + threadIdx.x;
    if (i < N) { cnt[i] = 0; deg[i] = 1.0f; }   // deg starts at self-loop weight
}

__global__ void k_hist(const int* __restrict__ dst, const float* __restrict__ w,
                       int* __restrict__ cnt, float* __restrict__ deg, int E) {
    int e = blockIdx.x * blockDim.x + threadIdx.x;
    if (e < E) {
        int d = dst[e];
        atomicAdd(&cnt[d], 1);
        atomicAdd(&deg[d], w[e]);
    }
}

__global__ void k_dinv(float* __restrict__ deg, int N) {
    int i = blockIdx.x * blockDim.x + threadIdx.x;
    if (i < N) deg[i] = rsqrtf(deg[i]);   // deg >= 1 (self loop), in place -> dinv
}

// block-level exclusive scan: 256 threads x 4 elems = 1024/block
__global__ __launch_bounds__(256) void k_scan1(const int* __restrict__ cnt, int* __restrict__ offs,
                                               int* __restrict__ bsum, int N) {
    __shared__ int sh[256];
    int t = threadIdx.x;
    int base = blockIdx.x * SCAN_CHUNK + t * 4;
    int c0 = (base + 0 < N) ? cnt[base + 0] : 0;
    int c1 = (base + 1 < N) ? cnt[base + 1] : 0;
    int c2 = (base + 2 < N) ? cnt[base + 2] : 0;
    int c3 = (base + 3 < N) ? cnt[base + 3] : 0;
    sh[t] = c0 + c1 + c2 + c3;
    __syncthreads();
    for (int off = 1; off < 256; off <<= 1) {
        int v = (t >= off) ? sh[t - off] : 0;
        __syncthreads();
        sh[t] += v;
        __syncthreads();
    }
    int run = (t > 0) ? sh[t - 1] : 0;
    if (base + 0 < N) offs[base + 0] = run; run += c0;
    if (base + 1 < N) offs[base + 1] = run; run += c1;
    if (base + 2 < N) offs[base + 2] = run; run += c2;
    if (base + 3 < N) offs[base + 3] = run;
    if (t == 255) bsum[blockIdx.x] = sh[255];
}

// scan the (<=128) block sums in one block
__global__ __launch_bounds__(128) void k_scan2(int* __restrict__ bsum, int nb) {
    __shared__ int sh[128];
    int t = threadIdx.x;
    int v0 = (t < nb) ? bsum[t] : 0;
    sh[t] = v0;
    __syncthreads();
    for (int off = 1; off < 128; off <<= 1) {
        int v = (t >= off) ? sh[t - off] : 0;
        __syncthreads();
        sh[t] += v;
        __syncthreads();
    }
    if (t < nb) bsum[t] = (t > 0) ? sh[t - 1] : 0;
}

// add block offsets; re-zero cnt for use as bin cursor; set offs[N]=E
__global__ void k_scan3(int* __restrict__ offs, const int* __restrict__ bsum,
                        int* __restrict__ cnt, int N, int E) {
    int i = blockIdx.x * blockDim.x + threadIdx.x;
    if (i < N) {
        offs[i] += bsum[i / SCAN_CHUNK];
        cnt[i] = 0;
    }
    if (i == 0) offs[N] = E;
}

// bin edges into CSR slots; fuse norm computation
__global__ void k_bin(const int* __restrict__ src, const int* __restrict__ dst,
                      const float* __restrict__ w, const float* __restrict__ dinv,
                      const int* __restrict__ offs, int* __restrict__ cur,
                      int* __restrict__ es, float* __restrict__ en, int E) {
    int e = blockIdx.x * blockDim.x + threadIdx.x;
    if (e < E) {
        int d = dst[e], s = src[e];
        int p = atomicAdd(&cur[d], 1);
        int idx = offs[d] + p;
        es[idx] = s;
        en[idx] = dinv[s] * w[e] * dinv[d];
    }
}

// ---------------- GEMM 1: h1 = x @ W1, x:[N,128] W1:[128,64] ----------------

__global__ __launch_bounds__(256) void k_gemm1(const float* __restrict__ x,
                                               const float* __restrict__ W,
                                               float* __restrict__ h, int N) {
    __shared__ float Ws[NFEAT * NHID];   // 32 KB
    __shared__ float xs[16][NFEAT];      // 8 KB
    int t = threadIdx.x;
    for (int i = t; i < NFEAT * NHID; i += 256) Ws[i] = W[i];
    int row0 = blockIdx.x * 16;
    for (int i = t; i < 16 * NFEAT; i += 256) {
        int r = i >> 7, k = i & 127;
        int row = row0 + r;
        xs[r][k] = (row < N) ? x[(size_t)row * NFEAT + k] : 0.0f;
    }
    __syncthreads();
    int c = t & 63;
    int rg = t >> 6;
    float acc[4] = {0.f, 0.f, 0.f, 0.f};
    #pragma unroll 4
    for (int k = 0; k < NFEAT; k++) {
        float wv = Ws[k * NHID + c];
        #pragma unroll
        for (int j = 0; j < 4; j++) acc[j] += xs[rg * 4 + j][k] * wv;
    }
    #pragma unroll
    for (int j = 0; j < 4; j++) {
        int row = row0 + rg * 4 + j;
        if (row < N) h[(size_t)row * NHID + c] = acc[j];
    }
}

// ---------------- aggregate layer 1: one wave per node, fused bias+ReLU ----------------

__global__ __launch_bounds__(256) void k_agg1(const int* __restrict__ offs, const int* __restrict__ es,
                                              const float* __restrict__ en, const float* __restrict__ h1,
                                              const float* __restrict__ dinv, const float* __restrict__ b1,
                                              float* __restrict__ out1, int N) {
    int wid = (blockIdx.x * blockDim.x + threadIdx.x) >> 6;
    if (wid >= N) return;
    int lane = threadIdx.x & 63;
    const int n = wid;
    int e = offs[n], end = offs[n + 1];
    float di = dinv[n];
    float acc0 = di * di * h1[(size_t)n * NHID + lane];  // self loop
    float acc1 = 0.f, acc2 = 0.f, acc3 = 0.f;
    for (; e + 4 <= end; e += 4) {
        int s0 = es[e], s1 = es[e + 1], s2 = es[e + 2], s3 = es[e + 3];
        float w0 = en[e], w1 = en[e + 1], w2 = en[e + 2], w3 = en[e + 3];
        acc0 += w0 * h1[(size_t)s0 * NHID + lane];
        acc1 += w1 * h1[(size_t)s1 * NHID + lane];
        acc2 += w2 * h1[(size_t)s2 * NHID + lane];
        acc3 += w3 * h1[(size_t)s3 * NHID + lane];
    }
    for (; e < end; e++) acc1 += en[e] * h1[(size_t)es[e] * NHID + lane];
    float acc = (acc0 + acc1) + (acc2 + acc3);
    out1[(size_t)n * NHID + lane] = fmaxf(acc + b1[lane], 0.f);  // fused bias + ReLU
}

// ---------------- GEMM 2: h2 = out1 @ W2 (out1 already ReLU'd), [N,64]x[64,40] ----------------

__global__ __launch_bounds__(320) void k_gemm2(const float* __restrict__ a,
                                               const float* __restrict__ W,
                                               float* __restrict__ h, int N) {
    __shared__ float Ws[NHID * NCLASS];
    __shared__ float xs[32][NHID];
    int t = threadIdx.x;
    for (int i = t; i < NHID * NCLASS; i += 320) Ws[i] = W[i];
    int row0 = blockIdx.x * 32;
    for (int i = t; i < 32 * NHID; i += 320) {
        int r = i >> 6, k = i & 63;
        int row = row0 + r;
        xs[r][k] = (row < N) ? a[(size_t)row * NHID + k] : 0.0f;
    }
    __syncthreads();
    int c = t % NCLASS;
    int rg = t / NCLASS;
    float acc[4] = {0.f, 0.f, 0.f, 0.f};
    #pragma unroll 4
    for (int k = 0; k < NHID; k++) {
        float wv = Ws[k * NCLASS + c];
        #pragma unroll
        for (int j = 0; j < 4; j++) acc[j] += xs[rg * 4 + j][k] * wv;
    }
    #pragma unroll
    for (int j = 0; j < 4; j++) {
        int row = row0 + rg * 4 + j;
        if (row < N) h[(size_t)row * NCLASS + c] = acc[j];
    }
}

// ---------------- aggregate layer 2 + bias + log_softmax fused, one wave per node ----------------

__global__ __launch_bounds__(256) void k_agg2(const int* __restrict__ offs, const int* __restrict__ es,
                                              const float* __restrict__ en, const float* __restrict__ h2,
                                              const float* __restrict__ dinv, const float* __restrict__ b2,
                                              float* __restrict__ out, int N) {
    int wid = (blockIdx.x * blockDim.x + threadIdx.x) >> 6;
    if (wid >= N) return;
    int lane = threadIdx.x & 63;
    int col = (lane < NCLASS) ? lane : 0;   // lanes >= 40 compute garbage, masked later
    const int n = wid;
    int e = offs[n], end = offs[n + 1];
    float di = dinv[n];
    float acc0 = di * di * h2[(size_t)n * NCLASS + col];
    float acc1 = 0.f, acc2 = 0.f, acc3 = 0.f;
    for (; e + 4 <= end; e += 4) {
        int s0 = es[e], s1 = es[e + 1], s2 = es[e + 2], s3 = es[e + 3];
        float w0 = en[e], w1 = en[e + 1], w2 = en[e + 2], w3 = en[e + 3];
        acc0 += w0 * h2[(size_t)s0 * NCLASS + col];
        acc1 += w1 * h2[(size_t)s1 * NCLASS + col];
        acc2 += w2 * h2[(size_t)s2 * NCLASS + col];
        acc3 += w3 * h2[(size_t)s3 * NCLASS + col];
    }
    for (; e < end; e++) acc1 += en[e] * h2[(size_t)es[e] * NCLASS + col];
    float v = (acc0 + acc1) + (acc2 + acc3) + b2[col];
    v = (lane < NCLASS) ? v : -INFINITY;
    // in-wave log_softmax over 40 cols
    float m = v;
    #pragma unroll
    for (int off = 32; off > 0; off >>= 1) m = fmaxf(m, __shfl_xor(m, off));
    float ex = (lane < NCLASS) ? expf(v - m) : 0.f;
    float s = ex;
    #pragma unroll
    for (int off = 32; off > 0; off >>= 1) s += __shfl_xor(s, off);
    if (lane < NCLASS) out[(size_t)n * NCLASS + lane] = v - m - logf(s);
}

// ---------------- launch ----------------

extern "C" void kernel_launch(void* const* d_in, const int* in_sizes, int n_in,
                              void* d_out, int out_size, void* d_ws, size_t ws_size,
                              hipStream_t stream) {
    const float* x  = (const float*)d_in[0];
    const int*   ei = (const int*)d_in[1];
    const float* w  = (const float*)d_in[2];
    const float* W1 = (const float*)d_in[3];
    const float* b1 = (const float*)d_in[4];
    const float* W2 = (const float*)d_in[5];
    const float* b2 = (const float*)d_in[6];
    float* out = (float*)d_out;

    const int N = in_sizes[0] / NFEAT;
    const int E = in_sizes[1] / 2;
    const int* src = ei;
    const int* dst = ei + E;

    // workspace layout (h2 aliases h1's region — h1 dead after agg1)
    int*   cnt  = (int*)d_ws;                        // N (hist count, then bin cursor)
    int*   offs = cnt + N;                           // N+1
    int*   es   = offs + N + 1;                      // E (CSR src)
    float* en   = (float*)(es + E);                  // E (CSR norm)
    float* dinv = en + E;                            // N (deg then rsqrt in place)
    float* h1   = dinv + N;                          // N*64
    float* out1 = h1 + (size_t)N * NHID;             // N*64
    int*   bsum = (int*)(out1 + (size_t)N * NHID);   // scan block sums (<=128)
    float* h2   = h1;                                // alias

    const int B = 256;
    const int nb_scan = (N + SCAN_CHUNK - 1) / SCAN_CHUNK;   // 98 <= 128

    // CSR build + norm
    k_setup<<<(N + B - 1) / B, B, 0, stream>>>(cnt, dinv, N);
    k_hist<<<(E + B - 1) / B, B, 0, stream>>>(dst, w, cnt, dinv, E);
    k_dinv<<<(N + B - 1) / B, B, 0, stream>>>(dinv, N);
    k_scan1<<<nb_scan, 256, 0, stream>>>(cnt, offs, bsum, N);
    k_scan2<<<1, 128, 0, stream>>>(bsum, nb_scan);
    k_scan3<<<(N + B - 1) / B, B, 0, stream>>>(offs, bsum, cnt, N, E);
    k_bin<<<(E + B - 1) / B, B, 0, stream>>>(src, dst, w, dinv, offs, cnt, es, en, E);

    // layer 1
    k_gemm1<<<(N + 15) / 16, 256, 0, stream>>>(x, W1, h1, N);
    k_agg1<<<(N + 3) / 4, 256, 0, stream>>>(offs, es, en, h1, dinv, b1, out1, N);

    // layer 2 (+ fused log_softmax)
    k_gemm2<<<(N + 31) / 32, 320, 0, stream>>>(out1, W2, h2, N);
    k_agg2<<<(N + 3) / 4, 256, 0, stream>>>(offs, es, en, h2, dinv, b2, out, N);
}

// Round 3
// 566.722 us; speedup vs baseline: 1.6556x; 1.0179x over previous
//
#include <hip/hip_runtime.h>
#include <math.h>

#define NFEAT 128
#define NHID 64
#define NCLASS 40
#define SCAN_CHUNK 1024   // elems per scan block (256 thr x 4)

// ---------------- CSR build ----------------

__global__ void k_setup(int* __restrict__ cnt, int N) {
    int i = blockIdx.x * blockDim.x + threadIdx.x;
    if (i < N) cnt[i] = 0;
}

// count in-degree only (single scattered atomic per edge)
__global__ void k_hist(const int* __restrict__ dst, int* __restrict__ cnt, int E) {
    int e = blockIdx.x * blockDim.x + threadIdx.x;
    if (e < E) atomicAdd(&cnt[dst[e]], 1);
}

// block-level exclusive scan: 256 threads x 4 elems = 1024/block
__global__ __launch_bounds__(256) void k_scan1(const int* __restrict__ cnt, int* __restrict__ offs,
                                               int* __restrict__ bsum, int N) {
    __shared__ int sh[256];
    int t = threadIdx.x;
    int base = blockIdx.x * SCAN_CHUNK + t * 4;
    int c0 = (base + 0 < N) ? cnt[base + 0] : 0;
    int c1 = (base + 1 < N) ? cnt[base + 1] : 0;
    int c2 = (base + 2 < N) ? cnt[base + 2] : 0;
    int c3 = (base + 3 < N) ? cnt[base + 3] : 0;
    sh[t] = c0 + c1 + c2 + c3;
    __syncthreads();
    for (int off = 1; off < 256; off <<= 1) {
        int v = (t >= off) ? sh[t - off] : 0;
        __syncthreads();
        sh[t] += v;
        __syncthreads();
    }
    int run = (t > 0) ? sh[t - 1] : 0;
    if (base + 0 < N) offs[base + 0] = run; run += c0;
    if (base + 1 < N) offs[base + 1] = run; run += c1;
    if (base + 2 < N) offs[base + 2] = run; run += c2;
    if (base + 3 < N) offs[base + 3] = run;
    if (t == 255) bsum[blockIdx.x] = sh[255];
}

__global__ __launch_bounds__(128) void k_scan2(int* __restrict__ bsum, int nb) {
    __shared__ int sh[128];
    int t = threadIdx.x;
    int v0 = (t < nb) ? bsum[t] : 0;
    sh[t] = v0;
    __syncthreads();
    for (int off = 1; off < 128; off <<= 1) {
        int v = (t >= off) ? sh[t - off] : 0;
        __syncthreads();
        sh[t] += v;
        __syncthreads();
    }
    if (t < nb) bsum[t] = (t > 0) ? sh[t - 1] : 0;
}

// add block offsets; re-zero cnt for use as bin cursor; set offs[N]=E
__global__ void k_scan3(int* __restrict__ offs, const int* __restrict__ bsum,
                        int* __restrict__ cnt, int N, int E) {
    int i = blockIdx.x * blockDim.x + threadIdx.x;
    if (i < N) {
        offs[i] += bsum[i / SCAN_CHUNK];
        cnt[i] = 0;
    }
    if (i == 0) offs[N] = E;
}

// bin edges into CSR slots: one interleaved int2 (src, raw w) per slot
__global__ void k_bin(const int* __restrict__ src, const int* __restrict__ dst,
                      const float* __restrict__ w, const int* __restrict__ offs,
                      int* __restrict__ cur, int2* __restrict__ csr, int E) {
    int e = blockIdx.x * blockDim.x + threadIdx.x;
    if (e < E) {
        int d = dst[e];
        int p = atomicAdd(&cur[d], 1);
        int2 v;
        v.x = src[e];
        v.y = __float_as_int(w[e]);
        csr[offs[d] + p] = v;
    }
}

// deg[n] = 1 + sum of raw w over CSR row (coalesced), dinv = rsqrt
__global__ __launch_bounds__(256) void k_deg(const int* __restrict__ offs, const int2* __restrict__ csr,
                                             float* __restrict__ dinv, int N) {
    int n = (blockIdx.x * blockDim.x + threadIdx.x) >> 6;
    if (n >= N) return;
    int lane = threadIdx.x & 63;
    int b = offs[n], end = offs[n + 1];
    float s = 0.f;
    for (int p = b + lane; p < end; p += 64) s += __int_as_float(csr[p].y);
    #pragma unroll
    for (int off = 32; off > 0; off >>= 1) s += __shfl_xor(s, off);
    if (lane == 0) dinv[n] = rsqrtf(1.0f + s);
}

// rewrite w -> norm = dinv[src]*w*dinv[dst] in place (coalesced rows)
__global__ __launch_bounds__(256) void k_normp(const int* __restrict__ offs, int2* __restrict__ csr,
                                               const float* __restrict__ dinv, int N) {
    int n = (blockIdx.x * blockDim.x + threadIdx.x) >> 6;
    if (n >= N) return;
    int lane = threadIdx.x & 63;
    int b = offs[n], end = offs[n + 1];
    float dn = dinv[n];
    for (int p = b + lane; p < end; p += 64) {
        int2 v = csr[p];
        v.y = __float_as_int(dinv[v.x] * __int_as_float(v.y) * dn);
        csr[p] = v;
    }
}

// ---------------- GEMM 1: h1 = x @ W1, x:[N,128] W1:[128,64] ----------------

__global__ __launch_bounds__(256) void k_gemm1(const float* __restrict__ x,
                                               const float* __restrict__ W,
                                               float* __restrict__ h, int N) {
    __shared__ float Ws[NFEAT * NHID];   // 32 KB
    __shared__ float xs[16][NFEAT];      // 8 KB
    int t = threadIdx.x;
    for (int i = t; i < NFEAT * NHID; i += 256) Ws[i] = W[i];
    int row0 = blockIdx.x * 16;
    for (int i = t; i < 16 * NFEAT; i += 256) {
        int r = i >> 7, k = i & 127;
        int row = row0 + r;
        xs[r][k] = (row < N) ? x[(size_t)row * NFEAT + k] : 0.0f;
    }
    __syncthreads();
    int c = t & 63;
    int rg = t >> 6;
    float acc[4] = {0.f, 0.f, 0.f, 0.f};
    #pragma unroll 4
    for (int k = 0; k < NFEAT; k++) {
        float wv = Ws[k * NHID + c];
        #pragma unroll
        for (int j = 0; j < 4; j++) acc[j] += xs[rg * 4 + j][k] * wv;
    }
    #pragma unroll
    for (int j = 0; j < 4; j++) {
        int row = row0 + rg * 4 + j;
        if (row < N) h[(size_t)row * NHID + c] = acc[j];
    }
}

// ---------------- aggregate layer 1: one wave per node, fused bias+ReLU ----------------

__global__ __launch_bounds__(256) void k_agg1(const int* __restrict__ offs, const int2* __restrict__ csr,
                                              const float* __restrict__ h1, const float* __restrict__ dinv,
                                              const float* __restrict__ b1, float* __restrict__ out1, int N) {
    int n = (blockIdx.x * blockDim.x + threadIdx.x) >> 6;
    if (n >= N) return;
    int lane = threadIdx.x & 63;
    int e = offs[n], end = offs[n + 1];
    float di = dinv[n];
    float acc0 = di * di * h1[(size_t)n * NHID + lane];  // self loop
    float acc1 = 0.f, acc2 = 0.f, acc3 = 0.f;
    for (; e + 4 <= end; e += 4) {
        int2 v0 = csr[e], v1 = csr[e + 1], v2 = csr[e + 2], v3 = csr[e + 3];
        acc0 += __int_as_float(v0.y) * h1[(size_t)v0.x * NHID + lane];
        acc1 += __int_as_float(v1.y) * h1[(size_t)v1.x * NHID + lane];
        acc2 += __int_as_float(v2.y) * h1[(size_t)v2.x * NHID + lane];
        acc3 += __int_as_float(v3.y) * h1[(size_t)v3.x * NHID + lane];
    }
    for (; e < end; e++) {
        int2 v = csr[e];
        acc1 += __int_as_float(v.y) * h1[(size_t)v.x * NHID + lane];
    }
    float acc = (acc0 + acc1) + (acc2 + acc3);
    out1[(size_t)n * NHID + lane] = fmaxf(acc + b1[lane], 0.f);  // fused bias + ReLU
}

// ---------------- GEMM 2: h2 = out1 @ W2 (already ReLU'd), [N,64]x[64,40] ----------------

__global__ __launch_bounds__(320) void k_gemm2(const float* __restrict__ a,
                                               const float* __restrict__ W,
                                               float* __restrict__ h, int N) {
    __shared__ float Ws[NHID * NCLASS];
    __shared__ float xs[32][NHID];
    int t = threadIdx.x;
    for (int i = t; i < NHID * NCLASS; i += 320) Ws[i] = W[i];
    int row0 = blockIdx.x * 32;
    for (int i = t; i < 32 * NHID; i += 320) {
        int r = i >> 6, k = i & 63;
        int row = row0 + r;
        xs[r][k] = (row < N) ? a[(size_t)row * NHID + k] : 0.0f;
    }
    __syncthreads();
    int c = t % NCLASS;
    int rg = t / NCLASS;
    float acc[4] = {0.f, 0.f, 0.f, 0.f};
    #pragma unroll 4
    for (int k = 0; k < NHID; k++) {
        float wv = Ws[k * NCLASS + c];
        #pragma unroll
        for (int j = 0; j < 4; j++) acc[j] += xs[rg * 4 + j][k] * wv;
    }
    #pragma unroll
    for (int j = 0; j < 4; j++) {
        int row = row0 + rg * 4 + j;
        if (row < N) h[(size_t)row * NCLASS + c] = acc[j];
    }
}

// ---------------- aggregate layer 2 + bias + log_softmax fused ----------------

__global__ __launch_bounds__(256) void k_agg2(const int* __restrict__ offs, const int2* __restrict__ csr,
                                              const float* __restrict__ h2, const float* __restrict__ dinv,
                                              const float* __restrict__ b2, float* __restrict__ out, int N) {
    int n = (blockIdx.x * blockDim.x + threadIdx.x) >> 6;
    if (n >= N) return;
    int lane = threadIdx.x & 63;
    int col = (lane < NCLASS) ? lane : 0;
    int e = offs[n], end = offs[n + 1];
    float di = dinv[n];
    float acc0 = di * di * h2[(size_t)n * NCLASS + col];
    float acc1 = 0.f, acc2 = 0.f, acc3 = 0.f;
    for (; e + 4 <= end; e += 4) {
        int2 v0 = csr[e], v1 = csr[e + 1], v2 = csr[e + 2], v3 = csr[e + 3];
        acc0 += __int_as_float(v0.y) * h2[(size_t)v0.x * NCLASS + col];
        acc1 += __int_as_float(v1.y) * h2[(size_t)v1.x * NCLASS + col];
        acc2 += __int_as_float(v2.y) * h2[(size_t)v2.x * NCLASS + col];
        acc3 += __int_as_float(v3.y) * h2[(size_t)v3.x * NCLASS + col];
    }
    for (; e < end; e++) {
        int2 v = csr[e];
        acc1 += __int_as_float(v.y) * h2[(size_t)v.x * NCLASS + col];
    }
    float v = (acc0 + acc1) + (acc2 + acc3) + b2[col];
    v = (lane < NCLASS) ? v : -INFINITY;
    float m = v;
    #pragma unroll
    for (int off = 32; off > 0; off >>= 1) m = fmaxf(m, __shfl_xor(m, off));
    float ex = (lane < NCLASS) ? expf(v - m) : 0.f;
    float s = ex;
    #pragma unroll
    for (int off = 32; off > 0; off >>= 1) s += __shfl_xor(s, off);
    if (lane < NCLASS) out[(size_t)n * NCLASS + lane] = v - m - logf(s);
}

// ---------------- launch ----------------

extern "C" void kernel_launch(void* const* d_in, const int* in_sizes, int n_in,
                              void* d_out, int out_size, void* d_ws, size_t ws_size,
                              hipStream_t stream) {
    const float* x  = (const float*)d_in[0];
    const int*   ei = (const int*)d_in[1];
    const float* w  = (const float*)d_in[2];
    const float* W1 = (const float*)d_in[3];
    const float* b1 = (const float*)d_in[4];
    const float* W2 = (const float*)d_in[5];
    const float* b2 = (const float*)d_in[6];
    float* out = (float*)d_out;

    const int N = in_sizes[0] / NFEAT;
    const int E = in_sizes[1] / 2;
    const int* src = ei;
    const int* dst = ei + E;

    // workspace layout (~65 MB): h2 aliases h1 (h1 dead after agg1)
    int*   cnt  = (int*)d_ws;                        // N (hist count, then bin cursor)
    int*   offs = cnt + N;                           // N+1
    int2*  csr  = (int2*)(offs + N + 1);             // E slots of (src, w/norm)
    float* dinv = (float*)(csr + E);                 // N
    float* h1   = dinv + N;                          // N*64
    float* out1 = h1 + (size_t)N * NHID;             // N*64
    int*   bsum = (int*)(out1 + (size_t)N * NHID);   // scan block sums (<=128)
    float* h2   = h1;                                // alias

    const int B = 256;
    const int nb_scan = (N + SCAN_CHUNK - 1) / SCAN_CHUNK;   // 98 <= 128

    // CSR build (counts only; deg/norm derived later from CSR, no float atomics)
    k_setup<<<(N + B - 1) / B, B, 0, stream>>>(cnt, N);
    k_hist<<<(E + B - 1) / B, B, 0, stream>>>(dst, cnt, E);
    k_scan1<<<nb_scan, 256, 0, stream>>>(cnt, offs, bsum, N);
    k_scan2<<<1, 128, 0, stream>>>(bsum, nb_scan);
    k_scan3<<<(N + B - 1) / B, B, 0, stream>>>(offs, bsum, cnt, N, E);
    k_bin<<<(E + B - 1) / B, B, 0, stream>>>(src, dst, w, offs, cnt, csr, E);
    k_deg<<<(N + 3) / 4, 256, 0, stream>>>(offs, csr, dinv, N);
    k_normp<<<(N + 3) / 4, 256, 0, stream>>>(offs, csr, dinv, N);

    // layer 1
    k_gemm1<<<(N + 15) / 16, 256, 0, stream>>>(x, W1, h1, N);
    k_agg1<<<(N + 3) / 4, 256, 0, stream>>>(offs, csr, h1, dinv, b1, out1, N);

    // layer 2 (+ fused log_softmax)
    k_gemm2<<<(N + 31) / 32, 320, 0, stream>>>(out1, W2, h2, N);
    k_agg2<<<(N + 3) / 4, 256, 0, stream>>>(offs, csr, h2, dinv, b2, out, N);
}